// Round 4
// baseline (1774.528 us; speedup 1.0000x reference)
//
#include <hip/hip_runtime.h>
#include <hip/hip_bf16.h>

#define NTOK 16384
#define HD 1024
#define NE 8
#define FD 4096
#define BM 128
#define MAXTILES 264  // max sum ceil(cnt_e/128) <= 263, padded

typedef short short8 __attribute__((ext_vector_type(8)));
typedef unsigned short ushort8 __attribute__((ext_vector_type(8)));
typedef float f32x4 __attribute__((ext_vector_type(4)));

__device__ __forceinline__ unsigned short f2bf(float f) {
    unsigned int u = __builtin_bit_cast(unsigned int, f);
    u += 0x7fffu + ((u >> 16) & 1u);   // RNE
    return (unsigned short)(u >> 16);
}

// Async global->LDS DMA, 16B per lane. LDS dest: wave-uniform base + lane*16
// (linear); swizzling is done on the GLOBAL source + the ds_read address
// (rule #21: linear dest + inverse-swz source + swz on read).
__device__ __forceinline__ void gld16(unsigned short* lds, const unsigned short* gp) {
    __builtin_amdgcn_global_load_lds(
        (const __attribute__((address_space(1))) unsigned int*)gp,
        (__attribute__((address_space(3))) unsigned int*)lds,
        16, 0, 0);
}

__global__ void zero16_kernel(uint4* __restrict__ p, int n16) {
    int t = blockIdx.x * 256 + threadIdx.x;
    if (t < n16) p[t] = make_uint4(0u, 0u, 0u, 0u);
}

// ---------------- Router: fp32 logits, top-2, renormalized weights ----------
__global__ __launch_bounds__(256)
void router_kernel(const float* __restrict__ X, const float* __restrict__ Wr,
                   float* __restrict__ logits_out, int* __restrict__ te,
                   float* __restrict__ tw) {
    int wave = threadIdx.x >> 6, lane = threadIdx.x & 63;
    int token = blockIdx.x * 4 + wave;
    const float* x = X + (size_t)token * HD;
    float acc[NE];
#pragma unroll
    for (int e = 0; e < NE; e++) acc[e] = 0.f;
#pragma unroll 4
    for (int j = 0; j < HD / 64; j++) {
        int i = lane + 64 * j;
        float xv = x[i];
        float4 w0 = *(const float4*)(Wr + (size_t)i * NE);
        float4 w1 = *(const float4*)(Wr + (size_t)i * NE + 4);
        acc[0] += xv * w0.x; acc[1] += xv * w0.y;
        acc[2] += xv * w0.z; acc[3] += xv * w0.w;
        acc[4] += xv * w1.x; acc[5] += xv * w1.y;
        acc[6] += xv * w1.z; acc[7] += xv * w1.w;
    }
#pragma unroll
    for (int off = 32; off >= 1; off >>= 1)
#pragma unroll
        for (int e = 0; e < NE; e++)
            acc[e] += __shfl_xor(acc[e], off, 64);
    if (lane < NE) logits_out[(size_t)token * NE + lane] = acc[lane];
    if (lane == 0) {
        int i1 = 0;
#pragma unroll
        for (int e = 1; e < NE; e++) if (acc[e] > acc[i1]) i1 = e;
        int i2 = (i1 == 0) ? 1 : 0;
#pragma unroll
        for (int e = 0; e < NE; e++) if (e != i1 && acc[e] > acc[i2]) i2 = e;
        float w0 = 1.f / (1.f + __expf(acc[i2] - acc[i1]));
        te[token * 2] = i1; te[token * 2 + 1] = i2;
        tw[token * 2] = w0; tw[token * 2 + 1] = 1.f - w0;
    }
}

// ---------------- Histogram / scan / scatter (bucket by expert) -------------
__global__ void hist_kernel(const int* __restrict__ te, int* __restrict__ meta) {
    __shared__ int c[NE];
    int t = threadIdx.x;
    if (t < NE) c[t] = 0;
    __syncthreads();
    int tok = blockIdx.x * 256 + t;
    atomicAdd(&c[te[tok * 2]], 1);
    atomicAdd(&c[te[tok * 2 + 1]], 1);
    __syncthreads();
    if (t < NE) atomicAdd(&meta[t], c[t]);
}

__global__ void scan_kernel(int* __restrict__ meta) {
    if (threadIdx.x == 0) {
        int* counts = meta;       // [0..7]
        int* offs   = meta + 8;   // [8..16]
        int* tb     = meta + 17;  // [17..25]
        int* cur    = meta + 26;  // [26..33]
        offs[0] = 0; tb[0] = 0;
        for (int e = 0; e < NE; e++) {
            offs[e + 1] = offs[e] + counts[e];
            tb[e + 1] = tb[e] + (counts[e] + BM - 1) / BM;
            cur[e] = offs[e];
        }
    }
}

__global__ void scatter_kernel(const int* __restrict__ te, const float* __restrict__ tw,
                               int* __restrict__ meta, int* __restrict__ tok_ids,
                               float* __restrict__ aw) {
    __shared__ int c[NE];
    __shared__ int base[NE];
    int t = threadIdx.x;
    if (t < NE) c[t] = 0;
    __syncthreads();
    int tok = blockIdx.x * 256 + t;
    int e0 = te[tok * 2], e1 = te[tok * 2 + 1];
    int i0 = atomicAdd(&c[e0], 1);
    int i1 = atomicAdd(&c[e1], 1);
    __syncthreads();
    if (t < NE) base[t] = atomicAdd(&meta[26 + t], c[t]);
    __syncthreads();
    int p0 = base[e0] + i0, p1 = base[e1] + i1;
    tok_ids[p0] = tok; aw[p0] = tw[tok * 2];
    tok_ids[p1] = tok; aw[p1] = tw[tok * 2 + 1];
}

// ---------------- fp32 -> bf16 converts ------------------------------------
__global__ void convert_x_kernel(const float* __restrict__ in, unsigned short* __restrict__ out) {
    size_t t = (size_t)blockIdx.x * 256 + threadIdx.x;
    float4 a = ((const float4*)in)[t * 2];
    float4 b = ((const float4*)in)[t * 2 + 1];
    ushort8 o;
    o[0] = f2bf(a.x); o[1] = f2bf(a.y); o[2] = f2bf(a.z); o[3] = f2bf(a.w);
    o[4] = f2bf(b.x); o[5] = f2bf(b.y); o[6] = f2bf(b.z); o[7] = f2bf(b.w);
    *(ushort8*)(out + t * 8) = o;
}

// in [E][R][C] fp32 -> out [E][C][R] bf16 (64x64 tiles)
__global__ __launch_bounds__(256)
void transpose_convert_kernel(const float* __restrict__ in, unsigned short* __restrict__ out,
                              int R, int C) {
    __shared__ float tile[64][65];
    int e = blockIdx.z;
    int c0 = blockIdx.x * 64, r0 = blockIdx.y * 64;
    const float* src = in + (size_t)e * R * C;
    unsigned short* dst = out + (size_t)e * R * C;
    int t = threadIdx.x;
#pragma unroll
    for (int i = 0; i < 4; i++) {
        int idx = t + i * 256;               // 0..1023
        int row = idx >> 4, c4 = (idx & 15) * 4;
        float4 v = *(const float4*)(src + (size_t)(r0 + row) * C + c0 + c4);
        tile[row][c4] = v.x; tile[row][c4 + 1] = v.y;
        tile[row][c4 + 2] = v.z; tile[row][c4 + 3] = v.w;
    }
    __syncthreads();
#pragma unroll
    for (int i = 0; i < 2; i++) {
        int idx = t + i * 256;               // 0..511
        int c = idx >> 3, rc = (idx & 7) * 8;
        ushort8 o;
#pragma unroll
        for (int j = 0; j < 8; j++) o[j] = f2bf(tile[rc + j][c]);
        *(ushort8*)(dst + (size_t)(c0 + c) * R + r0 + rc) = o;
    }
}

// ---------------- Pass A: h = silu(Xg @ W1) * (Xg @ W3), grouped ------------
// 128x128 tile, BK=32, dual-matmul (gate+up share A).
// Schedule: dbuf LDS + single barrier per compute; stage(next) issued BEFORE
// ds_read+MFMA of current (T3 minimal 2-phase). Frag reads XOR-swizzled:
// 64B rows -> granule ^= (row>>1)&3 turns the 8-way conflict into 2-way.
#define TA (128 * 32)   // shorts per 8KB tile buffer
__global__ __launch_bounds__(256, 2)
void moe_gemm_a(const unsigned short* __restrict__ Xb,
                const unsigned short* __restrict__ W1t,   // [E][F][H]
                const unsigned short* __restrict__ W3t,   // [E][F][H]
                unsigned short* __restrict__ hbuf,        // [32768][FC]
                const int* __restrict__ meta,
                const int* __restrict__ tok_ids,
                int f0, int FC) {
    const int* counts = meta;
    const int* offs = meta + 8;
    const int* tb = meta + 17;
    int by = blockIdx.y;
    if (by >= tb[NE]) return;
    int e = 0;
    while (by >= tb[e + 1]) e++;
    int tIdx = by - tb[e];
    int rowsBase = offs[e] + tIdx * BM;
    int rowsInTile = counts[e] - tIdx * BM;
    if (rowsInTile > BM) rowsInTile = BM;
    int n0 = blockIdx.x * 128;               // chunk-local F col base

    __shared__ unsigned short As[2 * TA];
    __shared__ unsigned short B1s[2 * TA];
    __shared__ unsigned short B3s[2 * TA];

    int t = threadIdx.x;
    int wave = t >> 6, lane = t & 63, q = lane >> 4, m = lane & 15;
    int wr = (wave >> 1) * 64, wc = (wave & 1) * 64;
    // staging: 2 calls per matrix (64 rows each), rows of 64B (4 chunks of 16B)
    int r0 = t >> 2;                         // row within call, 0..63
    int chk = t & 3;
    int pos8s = (chk ^ ((r0 >> 1) & 3)) * 8; // inverse-swizzled source chunk
    int rta = min(r0, rowsInTile - 1);
    int rtb = min(64 + r0, rowsInTile - 1);
    const unsigned short* apA = Xb + (size_t)tok_ids[rowsBase + rta] * HD + pos8s;
    const unsigned short* apB = Xb + (size_t)tok_ids[rowsBase + rtb] * HD + pos8s;
    const unsigned short* bp1a = W1t + ((size_t)e * FD + f0 + n0 + r0) * HD + pos8s;
    const unsigned short* bp1b = W1t + ((size_t)e * FD + f0 + n0 + 64 + r0) * HD + pos8s;
    const unsigned short* bp3a = W3t + ((size_t)e * FD + f0 + n0 + r0) * HD + pos8s;
    const unsigned short* bp3b = W3t + ((size_t)e * FD + f0 + n0 + 64 + r0) * HD + pos8s;
    // swizzled fragment read column offset (shorts): granule = q ^ ((m>>1)&3)
    int qs = (q ^ ((m >> 1) & 3)) * 8;

    f32x4 accg[4][4], accu[4][4];
#pragma unroll
    for (int ri = 0; ri < 4; ri++)
#pragma unroll
        for (int ci = 0; ci < 4; ci++) {
            accg[ri][ci] = (f32x4){0.f, 0.f, 0.f, 0.f};
            accu[ri][ci] = (f32x4){0.f, 0.f, 0.f, 0.f};
        }

    auto stage = [&](int buf, int kt) {
        unsigned short* a = As + buf * TA;
        unsigned short* b1 = B1s + buf * TA;
        unsigned short* b3 = B3s + buf * TA;
        gld16(a + t * 8, apA + kt);
        gld16(a + 2048 + t * 8, apB + kt);
        gld16(b1 + t * 8, bp1a + kt);
        gld16(b1 + 2048 + t * 8, bp1b + kt);
        gld16(b3 + t * 8, bp3a + kt);
        gld16(b3 + 2048 + t * 8, bp3b + kt);
    };
    auto compute = [&](int buf) {
        const unsigned short* a = As + buf * TA;
        const unsigned short* b1 = B1s + buf * TA;
        const unsigned short* b3 = B3s + buf * TA;
        short8 af[4], b1f[4], b3f[4];
#pragma unroll
        for (int ri = 0; ri < 4; ri++)
            af[ri] = *(const short8*)(a + (wr + ri * 16 + m) * 32 + qs);
#pragma unroll
        for (int ci = 0; ci < 4; ci++) {
            b1f[ci] = *(const short8*)(b1 + (wc + ci * 16 + m) * 32 + qs);
            b3f[ci] = *(const short8*)(b3 + (wc + ci * 16 + m) * 32 + qs);
        }
#pragma unroll
        for (int ri = 0; ri < 4; ri++)
#pragma unroll
            for (int ci = 0; ci < 4; ci++) {
                accg[ri][ci] = __builtin_amdgcn_mfma_f32_16x16x32_bf16(af[ri], b1f[ci], accg[ri][ci], 0, 0, 0);
                accu[ri][ci] = __builtin_amdgcn_mfma_f32_16x16x32_bf16(af[ri], b3f[ci], accu[ri][ci], 0, 0, 0);
            }
    };

    stage(0, 0);
    __syncthreads();
    for (int kt = 0; kt < HD; kt += 64) {
        stage(1, kt + 32);                   // kt+32 < HD always (HD mult of 64)
        compute(0);
        __syncthreads();
        if (kt + 64 < HD) stage(0, kt + 64);
        compute(1);
        __syncthreads();
    }

    // epilogue: SwiGLU, store bf16 h.  C/D layout: col=lane&15, row=q*4+reg
#pragma unroll
    for (int ri = 0; ri < 4; ri++)
#pragma unroll
        for (int ci = 0; ci < 4; ci++)
#pragma unroll
            for (int r = 0; r < 4; r++) {
                int rl = wr + ri * 16 + q * 4 + r;
                if (rl < rowsInTile) {
                    float g = accg[ri][ci][r], u = accu[ri][ci][r];
                    float hv = g * u / (1.f + __expf(-g));
                    hbuf[(size_t)(rowsBase + rl) * FC + n0 + wc + ci * 16 + m] = f2bf(hv);
                }
            }
}

// ---------------- Pass B: out += w * (h @ W2), grouped, atomic --------------
// 128x128 tile, BK=64 (32 MFMA per barrier), dbuf + single barrier per compute.
// 128B rows -> canonical 16-way conflict; granule ^= row&7 makes reads 2-way.
#define TBB (128 * 64)  // shorts per 16KB tile buffer
__global__ __launch_bounds__(256, 2)
void moe_gemm_b(const unsigned short* __restrict__ hbuf,  // [32768][FC]
                const unsigned short* __restrict__ W2t,   // [E][H][F]
                float* __restrict__ out,
                const int* __restrict__ meta,
                const int* __restrict__ tok_ids,
                const float* __restrict__ aw,
                int f0, int FC) {
    const int* counts = meta;
    const int* offs = meta + 8;
    const int* tb = meta + 17;
    int by = blockIdx.y;
    if (by >= tb[NE]) return;
    int e = 0;
    while (by >= tb[e + 1]) e++;
    int tIdx = by - tb[e];
    int rowsBase = offs[e] + tIdx * BM;
    int rowsInTile = counts[e] - tIdx * BM;
    if (rowsInTile > BM) rowsInTile = BM;
    int n0 = blockIdx.x * 128;               // H col base

    __shared__ unsigned short As[2 * TBB];
    __shared__ unsigned short Bs[2 * TBB];

    int t = threadIdx.x;
    int wave = t >> 6, lane = t & 63, q = lane >> 4, m = lane & 15;
    int wr = (wave >> 1) * 64, wc = (wave & 1) * 64;
    // staging: 4 calls per matrix (32 rows each), rows of 128B (8 chunks)
    int r0 = t >> 3;                         // row within call, 0..31
    int chk = t & 7;
    int pos8s = (chk ^ (r0 & 7)) * 8;        // inverse-swizzled source chunk
    const unsigned short* apc[4];
    const unsigned short* bpc[4];
#pragma unroll
    for (int c = 0; c < 4; c++) {
        int ar = min(32 * c + r0, rowsInTile - 1);
        apc[c] = hbuf + (size_t)(rowsBase + ar) * FC + pos8s;
        bpc[c] = W2t + ((size_t)e * HD + n0 + 32 * c + r0) * FD + f0 + pos8s;
    }
    // swizzled frag read offsets (shorts): granule = (kk*4+q) ^ (m&7)
    int g0 = ((q) ^ (m & 7)) * 8;            // kk=0
    int g1 = ((4 + q) ^ (m & 7)) * 8;        // kk=1

    f32x4 acc[4][4];
#pragma unroll
    for (int ri = 0; ri < 4; ri++)
#pragma unroll
        for (int ci = 0; ci < 4; ci++) acc[ri][ci] = (f32x4){0.f, 0.f, 0.f, 0.f};

    auto stage = [&](int buf, int kt) {
        unsigned short* a = As + buf * TBB;
        unsigned short* b = Bs + buf * TBB;
#pragma unroll
        for (int c = 0; c < 4; c++) {
            gld16(a + c * 2048 + t * 8, apc[c] + kt);
            gld16(b + c * 2048 + t * 8, bpc[c] + kt);
        }
    };
    auto compute = [&](int buf) {
        const unsigned short* a = As + buf * TBB;
        const unsigned short* b = Bs + buf * TBB;
        short8 af0[4], bf0[4], af1[4], bf1[4];
#pragma unroll
        for (int ri = 0; ri < 4; ri++) {
            af0[ri] = *(const short8*)(a + (wr + ri * 16 + m) * 64 + g0);
            af1[ri] = *(const short8*)(a + (wr + ri * 16 + m) * 64 + g1);
        }
#pragma unroll
        for (int ci = 0; ci < 4; ci++) {
            bf0[ci] = *(const short8*)(b + (wc + ci * 16 + m) * 64 + g0);
            bf1[ci] = *(const short8*)(b + (wc + ci * 16 + m) * 64 + g1);
        }
#pragma unroll
        for (int ri = 0; ri < 4; ri++)
#pragma unroll
            for (int ci = 0; ci < 4; ci++) {
                acc[ri][ci] = __builtin_amdgcn_mfma_f32_16x16x32_bf16(af0[ri], bf0[ci], acc[ri][ci], 0, 0, 0);
                acc[ri][ci] = __builtin_amdgcn_mfma_f32_16x16x32_bf16(af1[ri], bf1[ci], acc[ri][ci], 0, 0, 0);
            }
    };

    stage(0, 0);
    __syncthreads();
    for (int kt = 0; kt < FC; kt += 128) {
        stage(1, kt + 64);                   // kt+64 < FC always (FC mult of 128)
        compute(0);
        __syncthreads();
        if (kt + 128 < FC) stage(0, kt + 128);
        compute(1);
        __syncthreads();
    }

#pragma unroll
    for (int ri = 0; ri < 4; ri++)
#pragma unroll
        for (int ci = 0; ci < 4; ci++)
#pragma unroll
            for (int r = 0; r < 4; r++) {
                int rl = wr + ri * 16 + q * 4 + r;
                if (rl < rowsInTile) {
                    int arow = rowsBase + rl;
                    int tok = tok_ids[arow];
                    float w = aw[arow];
                    atomicAdd(out + (size_t)tok * HD + n0 + wc + ci * 16 + m,
                              acc[ri][ci][r] * w);
                }
            }
}

// ---------------- launch -----------------------------------------------------
extern "C" void kernel_launch(void* const* d_in, const int* in_sizes, int n_in,
                              void* d_out, int out_size, void* d_ws, size_t ws_size,
                              hipStream_t stream) {
    const float* X  = (const float*)d_in[0];
    const float* Wr = (const float*)d_in[1];
    const float* W1 = (const float*)d_in[2];
    const float* W2 = (const float*)d_in[3];
    const float* W3 = (const float*)d_in[4];
    float* out = (float*)d_out;
    float* logits_out = out + (size_t)NTOK * HD;

    char* ws = (char*)d_ws;
    size_t off = 0;
    auto alloc = [&](size_t bytes) -> void* {
        void* p = ws + off;
        off = (off + bytes + 255) & ~(size_t)255;
        return p;
    };
    unsigned short* Xb  = (unsigned short*)alloc((size_t)NTOK * HD * 2);
    unsigned short* W1t = (unsigned short*)alloc((size_t)NE * HD * FD * 2);
    unsigned short* W3t = (unsigned short*)alloc((size_t)NE * HD * FD * 2);
    unsigned short* W2t = (unsigned short*)alloc((size_t)NE * HD * FD * 2);
    int*   tok_ids = (int*)alloc((size_t)NTOK * 2 * 4);
    float* awf     = (float*)alloc((size_t)NTOK * 2 * 4);
    int*   te      = (int*)alloc((size_t)NTOK * 2 * 4);
    float* twf     = (float*)alloc((size_t)NTOK * 2 * 4);
    int*   meta    = (int*)alloc(64 * 4);
    size_t remain = ws_size > off ? ws_size - off : 0;
    int NC = 1;
    while ((size_t)NTOK * 2 * (size_t)(FD / NC) * 2 > remain && NC < 32) NC *= 2;
    int FC = FD / NC;
    unsigned short* hbuf = (unsigned short*)(ws + off);

    // zero out (atomic accumulation target) and meta
    zero16_kernel<<<(NTOK * HD * 4 / 16 + 255) / 256, 256, 0, stream>>>((uint4*)out, NTOK * HD * 4 / 16);
    zero16_kernel<<<1, 256, 0, stream>>>((uint4*)meta, 16);

    router_kernel<<<NTOK / 4, 256, 0, stream>>>(X, Wr, logits_out, te, twf);
    hist_kernel<<<NTOK / 256, 256, 0, stream>>>(te, meta);
    scan_kernel<<<1, 64, 0, stream>>>(meta);
    scatter_kernel<<<NTOK / 256, 256, 0, stream>>>(te, twf, meta, tok_ids, awf);

    convert_x_kernel<<<NTOK * HD / 8 / 256, 256, 0, stream>>>(X, Xb);
    transpose_convert_kernel<<<dim3(FD / 64, HD / 64, NE), 256, 0, stream>>>(W1, W1t, HD, FD);
    transpose_convert_kernel<<<dim3(FD / 64, HD / 64, NE), 256, 0, stream>>>(W3, W3t, HD, FD);
    transpose_convert_kernel<<<dim3(HD / 64, FD / 64, NE), 256, 0, stream>>>(W2, W2t, FD, HD);

    for (int c = 0; c < NC; c++) {
        moe_gemm_a<<<dim3(FC / 128, MAXTILES), 256, 0, stream>>>(Xb, W1t, W3t, hbuf, meta, tok_ids, c * FC, FC);
        moe_gemm_b<<<dim3(HD / 128, MAXTILES), 256, 0, stream>>>(hbuf, W2t, out, meta, tok_ids, awf, c * FC, FC);
    }
}

// Round 5
// 1654.662 us; speedup vs baseline: 1.0724x; 1.0724x over previous
//
#include <hip/hip_runtime.h>
#include <hip/hip_bf16.h>

#define NTOK 16384
#define HD 1024
#define NE 8
#define FD 4096
#define BM 128
#define MAXTILES 264  // max sum ceil(cnt_e/128) <= 263, padded

typedef short short8 __attribute__((ext_vector_type(8)));
typedef unsigned short ushort8 __attribute__((ext_vector_type(8)));
typedef float f32x4 __attribute__((ext_vector_type(4)));

__device__ __forceinline__ unsigned short f2bf(float f) {
    unsigned int u = __builtin_bit_cast(unsigned int, f);
    u += 0x7fffu + ((u >> 16) & 1u);   // RNE
    return (unsigned short)(u >> 16);
}

// Async global->LDS DMA, 16B per lane. LDS dest: wave-uniform base + lane*16
// (linear); swizzling is done on the GLOBAL source + the ds_read address
// (rule #21: linear dest + inverse-swz source + swz on read).
__device__ __forceinline__ void gld16(unsigned short* lds, const unsigned short* gp) {
    __builtin_amdgcn_global_load_lds(
        (const __attribute__((address_space(1))) unsigned int*)gp,
        (__attribute__((address_space(3))) unsigned int*)lds,
        16, 0, 0);
}

__global__ void zero16_kernel(uint4* __restrict__ p, int n16) {
    int t = blockIdx.x * 256 + threadIdx.x;
    if (t < n16) p[t] = make_uint4(0u, 0u, 0u, 0u);
}

// ---------------- Router: fp32 logits, top-2, renormalized weights ----------
__global__ __launch_bounds__(256)
void router_kernel(const float* __restrict__ X, const float* __restrict__ Wr,
                   float* __restrict__ logits_out, int* __restrict__ te,
                   float* __restrict__ tw) {
    int wave = threadIdx.x >> 6, lane = threadIdx.x & 63;
    int token = blockIdx.x * 4 + wave;
    const float* x = X + (size_t)token * HD;
    float acc[NE];
#pragma unroll
    for (int e = 0; e < NE; e++) acc[e] = 0.f;
#pragma unroll 4
    for (int j = 0; j < HD / 64; j++) {
        int i = lane + 64 * j;
        float xv = x[i];
        float4 w0 = *(const float4*)(Wr + (size_t)i * NE);
        float4 w1 = *(const float4*)(Wr + (size_t)i * NE + 4);
        acc[0] += xv * w0.x; acc[1] += xv * w0.y;
        acc[2] += xv * w0.z; acc[3] += xv * w0.w;
        acc[4] += xv * w1.x; acc[5] += xv * w1.y;
        acc[6] += xv * w1.z; acc[7] += xv * w1.w;
    }
#pragma unroll
    for (int off = 32; off >= 1; off >>= 1)
#pragma unroll
        for (int e = 0; e < NE; e++)
            acc[e] += __shfl_xor(acc[e], off, 64);
    if (lane < NE) logits_out[(size_t)token * NE + lane] = acc[lane];
    if (lane == 0) {
        int i1 = 0;
#pragma unroll
        for (int e = 1; e < NE; e++) if (acc[e] > acc[i1]) i1 = e;
        int i2 = (i1 == 0) ? 1 : 0;
#pragma unroll
        for (int e = 0; e < NE; e++) if (e != i1 && acc[e] > acc[i2]) i2 = e;
        float w0 = 1.f / (1.f + __expf(acc[i2] - acc[i1]));
        te[token * 2] = i1; te[token * 2 + 1] = i2;
        tw[token * 2] = w0; tw[token * 2 + 1] = 1.f - w0;
    }
}

// ---------------- Histogram / scan / scatter (bucket by expert) -------------
__global__ void hist_kernel(const int* __restrict__ te, int* __restrict__ meta) {
    __shared__ int c[NE];
    int t = threadIdx.x;
    if (t < NE) c[t] = 0;
    __syncthreads();
    int tok = blockIdx.x * 256 + t;
    atomicAdd(&c[te[tok * 2]], 1);
    atomicAdd(&c[te[tok * 2 + 1]], 1);
    __syncthreads();
    if (t < NE) atomicAdd(&meta[t], c[t]);
}

__global__ void scan_kernel(int* __restrict__ meta) {
    if (threadIdx.x == 0) {
        int* counts = meta;       // [0..7]
        int* offs   = meta + 8;   // [8..16]
        int* tb     = meta + 17;  // [17..25]
        int* cur    = meta + 26;  // [26..33]
        offs[0] = 0; tb[0] = 0;
        for (int e = 0; e < NE; e++) {
            offs[e + 1] = offs[e] + counts[e];
            tb[e + 1] = tb[e] + (counts[e] + BM - 1) / BM;
            cur[e] = offs[e];
        }
    }
}

__global__ void scatter_kernel(const int* __restrict__ te, const float* __restrict__ tw,
                               int* __restrict__ meta, int* __restrict__ tok_ids,
                               float* __restrict__ aw) {
    __shared__ int c[NE];
    __shared__ int base[NE];
    int t = threadIdx.x;
    if (t < NE) c[t] = 0;
    __syncthreads();
    int tok = blockIdx.x * 256 + t;
    int e0 = te[tok * 2], e1 = te[tok * 2 + 1];
    int i0 = atomicAdd(&c[e0], 1);
    int i1 = atomicAdd(&c[e1], 1);
    __syncthreads();
    if (t < NE) base[t] = atomicAdd(&meta[26 + t], c[t]);
    __syncthreads();
    int p0 = base[e0] + i0, p1 = base[e1] + i1;
    tok_ids[p0] = tok; aw[p0] = tw[tok * 2];
    tok_ids[p1] = tok; aw[p1] = tw[tok * 2 + 1];
}

// ---------------- fp32 -> bf16 converts ------------------------------------
__global__ void convert_x_kernel(const float* __restrict__ in, unsigned short* __restrict__ out) {
    size_t t = (size_t)blockIdx.x * 256 + threadIdx.x;
    float4 a = ((const float4*)in)[t * 2];
    float4 b = ((const float4*)in)[t * 2 + 1];
    ushort8 o;
    o[0] = f2bf(a.x); o[1] = f2bf(a.y); o[2] = f2bf(a.z); o[3] = f2bf(a.w);
    o[4] = f2bf(b.x); o[5] = f2bf(b.y); o[6] = f2bf(b.z); o[7] = f2bf(b.w);
    *(ushort8*)(out + t * 8) = o;
}

// in [E][R][C] fp32 -> out [E][C][R] bf16 (64x64 tiles)
__global__ __launch_bounds__(256)
void transpose_convert_kernel(const float* __restrict__ in, unsigned short* __restrict__ out,
                              int R, int C) {
    __shared__ float tile[64][65];
    int e = blockIdx.z;
    int c0 = blockIdx.x * 64, r0 = blockIdx.y * 64;
    const float* src = in + (size_t)e * R * C;
    unsigned short* dst = out + (size_t)e * R * C;
    int t = threadIdx.x;
#pragma unroll
    for (int i = 0; i < 4; i++) {
        int idx = t + i * 256;               // 0..1023
        int row = idx >> 4, c4 = (idx & 15) * 4;
        float4 v = *(const float4*)(src + (size_t)(r0 + row) * C + c0 + c4);
        tile[row][c4] = v.x; tile[row][c4 + 1] = v.y;
        tile[row][c4 + 2] = v.z; tile[row][c4 + 3] = v.w;
    }
    __syncthreads();
#pragma unroll
    for (int i = 0; i < 2; i++) {
        int idx = t + i * 256;               // 0..511
        int c = idx >> 3, rc = (idx & 7) * 8;
        ushort8 o;
#pragma unroll
        for (int j = 0; j < 8; j++) o[j] = f2bf(tile[rc + j][c]);
        *(ushort8*)(dst + (size_t)(c0 + c) * R + r0 + rc) = o;
    }
}

// ---------------- Pass A: h = silu(Xg @ W1) * (Xg @ W3), grouped ------------
// 128x128 tile, BK=32, dual-matmul (gate+up share A).
// T4 schedule: dbuf LDS, raw s_barrier + COUNTED vmcnt(6) — the newer stage's
// 6 global_load_lds stay in flight across barriers; only the older stage is
// drained before its buffer is read. No __syncthreads (it drains vmcnt(0)).
#define TA (128 * 32)   // shorts per 8KB tile buffer
__global__ __launch_bounds__(256, 2)
void moe_gemm_a(const unsigned short* __restrict__ Xb,
                const unsigned short* __restrict__ W1t,   // [E][F][H]
                const unsigned short* __restrict__ W3t,   // [E][F][H]
                unsigned short* __restrict__ hbuf,        // [32768][FC]
                const int* __restrict__ meta,
                const int* __restrict__ tok_ids,
                int f0, int FC) {
    const int* counts = meta;
    const int* offs = meta + 8;
    const int* tb = meta + 17;
    int by = blockIdx.y;
    if (by >= tb[NE]) return;
    int e = 0;
    while (by >= tb[e + 1]) e++;
    int tIdx = by - tb[e];
    int rowsBase = offs[e] + tIdx * BM;
    int rowsInTile = counts[e] - tIdx * BM;
    if (rowsInTile > BM) rowsInTile = BM;
    int n0 = blockIdx.x * 128;               // chunk-local F col base

    __shared__ unsigned short As[2 * TA];
    __shared__ unsigned short B1s[2 * TA];
    __shared__ unsigned short B3s[2 * TA];

    int t = threadIdx.x;
    int wave = t >> 6, lane = t & 63, q = lane >> 4, m = lane & 15;
    int wr = (wave >> 1) * 64, wc = (wave & 1) * 64;
    // staging: 2 calls per matrix (64 rows each), rows of 64B (4 chunks of 16B)
    int r0 = t >> 2;                         // row within call, 0..63
    int chk = t & 3;
    int pos8s = (chk ^ ((r0 >> 1) & 3)) * 8; // inverse-swizzled source chunk
    int rta = min(r0, rowsInTile - 1);
    int rtb = min(64 + r0, rowsInTile - 1);
    const unsigned short* apA = Xb + (size_t)tok_ids[rowsBase + rta] * HD + pos8s;
    const unsigned short* apB = Xb + (size_t)tok_ids[rowsBase + rtb] * HD + pos8s;
    const unsigned short* bp1a = W1t + ((size_t)e * FD + f0 + n0 + r0) * HD + pos8s;
    const unsigned short* bp1b = W1t + ((size_t)e * FD + f0 + n0 + 64 + r0) * HD + pos8s;
    const unsigned short* bp3a = W3t + ((size_t)e * FD + f0 + n0 + r0) * HD + pos8s;
    const unsigned short* bp3b = W3t + ((size_t)e * FD + f0 + n0 + 64 + r0) * HD + pos8s;
    // swizzled fragment read column offset (shorts): granule = q ^ ((m>>1)&3)
    int qs = (q ^ ((m >> 1) & 3)) * 8;

    f32x4 accg[4][4], accu[4][4];
#pragma unroll
    for (int ri = 0; ri < 4; ri++)
#pragma unroll
        for (int ci = 0; ci < 4; ci++) {
            accg[ri][ci] = (f32x4){0.f, 0.f, 0.f, 0.f};
            accu[ri][ci] = (f32x4){0.f, 0.f, 0.f, 0.f};
        }

    auto stage = [&](int buf, int kt) {
        unsigned short* a = As + buf * TA;
        unsigned short* b1 = B1s + buf * TA;
        unsigned short* b3 = B3s + buf * TA;
        gld16(a + t * 8, apA + kt);
        gld16(a + 2048 + t * 8, apB + kt);
        gld16(b1 + t * 8, bp1a + kt);
        gld16(b1 + 2048 + t * 8, bp1b + kt);
        gld16(b3 + t * 8, bp3a + kt);
        gld16(b3 + 2048 + t * 8, bp3b + kt);
    };
    auto compute = [&](int buf) {
        const unsigned short* a = As + buf * TA;
        const unsigned short* b1 = B1s + buf * TA;
        const unsigned short* b3 = B3s + buf * TA;
        short8 af[4], b1f[4], b3f[4];
#pragma unroll
        for (int ri = 0; ri < 4; ri++)
            af[ri] = *(const short8*)(a + (wr + ri * 16 + m) * 32 + qs);
#pragma unroll
        for (int ci = 0; ci < 4; ci++) {
            b1f[ci] = *(const short8*)(b1 + (wc + ci * 16 + m) * 32 + qs);
            b3f[ci] = *(const short8*)(b3 + (wc + ci * 16 + m) * 32 + qs);
        }
#pragma unroll
        for (int ri = 0; ri < 4; ri++)
#pragma unroll
            for (int ci = 0; ci < 4; ci++) {
                accg[ri][ci] = __builtin_amdgcn_mfma_f32_16x16x32_bf16(af[ri], b1f[ci], accg[ri][ci], 0, 0, 0);
                accu[ri][ci] = __builtin_amdgcn_mfma_f32_16x16x32_bf16(af[ri], b3f[ci], accu[ri][ci], 0, 0, 0);
            }
    };

    stage(0, 0);
    for (int kt = 0; kt < HD; kt += 64) {
        stage(1, kt + 32);                   // kt+32 < HD always (HD mult of 64)
        // wait only for stage(0)'s 6 loads; stage(1)'s 6 remain in flight
        asm volatile("s_waitcnt vmcnt(6)" ::: "memory");
        __builtin_amdgcn_s_barrier();
        compute(0);
        __builtin_amdgcn_s_barrier();        // readers done before buf0 reuse
        if (kt + 64 < HD) {
            stage(0, kt + 64);
            asm volatile("s_waitcnt vmcnt(6)" ::: "memory");
        } else {
            asm volatile("s_waitcnt vmcnt(0)" ::: "memory");
        }
        __builtin_amdgcn_s_barrier();
        compute(1);
        __builtin_amdgcn_s_barrier();        // readers done before buf1 reuse
    }

    // epilogue: SwiGLU, store bf16 h.  C/D layout: col=lane&15, row=q*4+reg
#pragma unroll
    for (int ri = 0; ri < 4; ri++)
#pragma unroll
        for (int ci = 0; ci < 4; ci++)
#pragma unroll
            for (int r = 0; r < 4; r++) {
                int rl = wr + ri * 16 + q * 4 + r;
                if (rl < rowsInTile) {
                    float g = accg[ri][ci][r], u = accu[ri][ci][r];
                    float hv = g * u / (1.f + __expf(-g));
                    hbuf[(size_t)(rowsBase + rl) * FC + n0 + wc + ci * 16 + m] = f2bf(hv);
                }
            }
}

// ---------------- Pass B: out += w * (h @ W2), grouped, atomic --------------
// 128x128 tile, BK=64 (32 MFMA per compute), same T4 counted-vmcnt schedule
// with 8 loads per stage -> vmcnt(8).
#define TBB (128 * 64)  // shorts per 16KB tile buffer
__global__ __launch_bounds__(256, 2)
void moe_gemm_b(const unsigned short* __restrict__ hbuf,  // [32768][FC]
                const unsigned short* __restrict__ W2t,   // [E][H][F]
                float* __restrict__ out,
                const int* __restrict__ meta,
                const int* __restrict__ tok_ids,
                const float* __restrict__ aw,
                int f0, int FC) {
    const int* counts = meta;
    const int* offs = meta + 8;
    const int* tb = meta + 17;
    int by = blockIdx.y;
    if (by >= tb[NE]) return;
    int e = 0;
    while (by >= tb[e + 1]) e++;
    int tIdx = by - tb[e];
    int rowsBase = offs[e] + tIdx * BM;
    int rowsInTile = counts[e] - tIdx * BM;
    if (rowsInTile > BM) rowsInTile = BM;
    int n0 = blockIdx.x * 128;               // H col base

    __shared__ unsigned short As[2 * TBB];
    __shared__ unsigned short Bs[2 * TBB];

    int t = threadIdx.x;
    int wave = t >> 6, lane = t & 63, q = lane >> 4, m = lane & 15;
    int wr = (wave >> 1) * 64, wc = (wave & 1) * 64;
    // staging: 4 calls per matrix (32 rows each), rows of 128B (8 chunks)
    int r0 = t >> 3;                         // row within call, 0..31
    int chk = t & 7;
    int pos8s = (chk ^ (r0 & 7)) * 8;        // inverse-swizzled source chunk
    const unsigned short* apc[4];
    const unsigned short* bpc[4];
#pragma unroll
    for (int c = 0; c < 4; c++) {
        int ar = min(32 * c + r0, rowsInTile - 1);
        apc[c] = hbuf + (size_t)(rowsBase + ar) * FC + pos8s;
        bpc[c] = W2t + ((size_t)e * HD + n0 + 32 * c + r0) * FD + f0 + pos8s;
    }
    // swizzled frag read offsets (shorts): granule = (kk*4+q) ^ (m&7)
    int g0 = ((q) ^ (m & 7)) * 8;            // kk=0
    int g1 = ((4 + q) ^ (m & 7)) * 8;        // kk=1

    f32x4 acc[4][4];
#pragma unroll
    for (int ri = 0; ri < 4; ri++)
#pragma unroll
        for (int ci = 0; ci < 4; ci++) acc[ri][ci] = (f32x4){0.f, 0.f, 0.f, 0.f};

    auto stage = [&](int buf, int kt) {
        unsigned short* a = As + buf * TBB;
        unsigned short* b = Bs + buf * TBB;
#pragma unroll
        for (int c = 0; c < 4; c++) {
            gld16(a + c * 2048 + t * 8, apc[c] + kt);
            gld16(b + c * 2048 + t * 8, bpc[c] + kt);
        }
    };
    auto compute = [&](int buf) {
        const unsigned short* a = As + buf * TBB;
        const unsigned short* b = Bs + buf * TBB;
        short8 af0[4], bf0[4], af1[4], bf1[4];
#pragma unroll
        for (int ri = 0; ri < 4; ri++) {
            af0[ri] = *(const short8*)(a + (wr + ri * 16 + m) * 64 + g0);
            af1[ri] = *(const short8*)(a + (wr + ri * 16 + m) * 64 + g1);
        }
#pragma unroll
        for (int ci = 0; ci < 4; ci++) {
            bf0[ci] = *(const short8*)(b + (wc + ci * 16 + m) * 64 + g0);
            bf1[ci] = *(const short8*)(b + (wc + ci * 16 + m) * 64 + g1);
        }
#pragma unroll
        for (int ri = 0; ri < 4; ri++)
#pragma unroll
            for (int ci = 0; ci < 4; ci++) {
                acc[ri][ci] = __builtin_amdgcn_mfma_f32_16x16x32_bf16(af0[ri], bf0[ci], acc[ri][ci], 0, 0, 0);
                acc[ri][ci] = __builtin_amdgcn_mfma_f32_16x16x32_bf16(af1[ri], bf1[ci], acc[ri][ci], 0, 0, 0);
            }
    };

    stage(0, 0);
    for (int kt = 0; kt < FC; kt += 128) {
        stage(1, kt + 64);                   // kt+64 < FC always (FC mult of 128)
        asm volatile("s_waitcnt vmcnt(8)" ::: "memory");
        __builtin_amdgcn_s_barrier();
        compute(0);
        __builtin_amdgcn_s_barrier();
        if (kt + 128 < FC) {
            stage(0, kt + 128);
            asm volatile("s_waitcnt vmcnt(8)" ::: "memory");
        } else {
            asm volatile("s_waitcnt vmcnt(0)" ::: "memory");
        }
        __builtin_amdgcn_s_barrier();
        compute(1);
        __builtin_amdgcn_s_barrier();
    }

#pragma unroll
    for (int ri = 0; ri < 4; ri++)
#pragma unroll
        for (int ci = 0; ci < 4; ci++)
#pragma unroll
            for (int r = 0; r < 4; r++) {
                int rl = wr + ri * 16 + q * 4 + r;
                if (rl < rowsInTile) {
                    int arow = rowsBase + rl;
                    int tok = tok_ids[arow];
                    float w = aw[arow];
                    atomicAdd(out + (size_t)tok * HD + n0 + wc + ci * 16 + m,
                              acc[ri][ci][r] * w);
                }
            }
}

// ---------------- launch -----------------------------------------------------
extern "C" void kernel_launch(void* const* d_in, const int* in_sizes, int n_in,
                              void* d_out, int out_size, void* d_ws, size_t ws_size,
                              hipStream_t stream) {
    const float* X  = (const float*)d_in[0];
    const float* Wr = (const float*)d_in[1];
    const float* W1 = (const float*)d_in[2];
    const float* W2 = (const float*)d_in[3];
    const float* W3 = (const float*)d_in[4];
    float* out = (float*)d_out;
    float* logits_out = out + (size_t)NTOK * HD;

    char* ws = (char*)d_ws;
    size_t off = 0;
    auto alloc = [&](size_t bytes) -> void* {
        void* p = ws + off;
        off = (off + bytes + 255) & ~(size_t)255;
        return p;
    };
    unsigned short* Xb  = (unsigned short*)alloc((size_t)NTOK * HD * 2);
    unsigned short* W1t = (unsigned short*)alloc((size_t)NE * HD * FD * 2);
    unsigned short* W3t = (unsigned short*)alloc((size_t)NE * HD * FD * 2);
    unsigned short* W2t = (unsigned short*)alloc((size_t)NE * HD * FD * 2);
    int*   tok_ids = (int*)alloc((size_t)NTOK * 2 * 4);
    float* awf     = (float*)alloc((size_t)NTOK * 2 * 4);
    int*   te      = (int*)alloc((size_t)NTOK * 2 * 4);
    float* twf     = (float*)alloc((size_t)NTOK * 2 * 4);
    int*   meta    = (int*)alloc(64 * 4);
    size_t remain = ws_size > off ? ws_size - off : 0;
    int NC = 1;
    while ((size_t)NTOK * 2 * (size_t)(FD / NC) * 2 > remain && NC < 32) NC *= 2;
    int FC = FD / NC;
    unsigned short* hbuf = (unsigned short*)(ws + off);

    // zero out (atomic accumulation target) and meta
    zero16_kernel<<<(NTOK * HD * 4 / 16 + 255) / 256, 256, 0, stream>>>((uint4*)out, NTOK * HD * 4 / 16);
    zero16_kernel<<<1, 256, 0, stream>>>((uint4*)meta, 16);

    router_kernel<<<NTOK / 4, 256, 0, stream>>>(X, Wr, logits_out, te, twf);
    hist_kernel<<<NTOK / 256, 256, 0, stream>>>(te, meta);
    scan_kernel<<<1, 64, 0, stream>>>(meta);
    scatter_kernel<<<NTOK / 256, 256, 0, stream>>>(te, twf, meta, tok_ids, awf);

    convert_x_kernel<<<NTOK * HD / 8 / 256, 256, 0, stream>>>(X, Xb);
    transpose_convert_kernel<<<dim3(FD / 64, HD / 64, NE), 256, 0, stream>>>(W1, W1t, HD, FD);
    transpose_convert_kernel<<<dim3(FD / 64, HD / 64, NE), 256, 0, stream>>>(W3, W3t, HD, FD);
    transpose_convert_kernel<<<dim3(HD / 64, FD / 64, NE), 256, 0, stream>>>(W2, W2t, FD, HD);

    for (int c = 0; c < NC; c++) {
        moe_gemm_a<<<dim3(FC / 128, MAXTILES), 256, 0, stream>>>(Xb, W1t, W3t, hbuf, meta, tok_ids, c * FC, FC);
        moe_gemm_b<<<dim3(HD / 128, MAXTILES), 256, 0, stream>>>(hbuf, W2t, out, meta, tok_ids, awf, c * FC, FC);
    }
}